// Round 16
// baseline (194.282 us; speedup 1.0000x reference)
//
#include <hip/hip_runtime.h>
#include <math.h>

#define EPS 1e-5f

typedef float __attribute__((ext_vector_type(4))) floatx4;

__device__ __forceinline__ float sigmoidf_(float v){ return 1.0f/(1.0f+expf(-v)); }

// ---------------- K1: per-(bg,c) row sums, col sums, total, corners (8192 blocks) ----------------
__global__ __launch_bounds__(256) void k1_rowcol(const float* __restrict__ x,
    float* __restrict__ rs, float* __restrict__ cs, float* __restrict__ chansum,
    float* __restrict__ corners)
{
    const int bgc = blockIdx.x;
    const int tid = threadIdx.x;
    __shared__ float srow[64];
    __shared__ float scol[64];
    if (tid < 64) scol[tid] = 0.0f;
    __syncthreads();
    const float4* x4 = (const float4*)(x + (size_t)bgc * 4096);
    float c0=0.f,c1=0.f,c2=0.f,c3=0.f;
    #pragma unroll
    for (int it=0; it<4; ++it){
        int f = it*256 + tid;
        float4 v = x4[f];
        int i = f >> 4;
        float rsum = v.x+v.y+v.z+v.w;
        rsum += __shfl_xor(rsum, 1);
        rsum += __shfl_xor(rsum, 2);
        rsum += __shfl_xor(rsum, 4);
        rsum += __shfl_xor(rsum, 8);
        if ((tid & 15)==0) srow[i] = rsum;
        c0+=v.x; c1+=v.y; c2+=v.z; c3+=v.w;
    }
    int jb = (tid & 15)*4;
    atomicAdd(&scol[jb+0], c0);
    atomicAdd(&scol[jb+1], c1);
    atomicAdd(&scol[jb+2], c2);
    atomicAdd(&scol[jb+3], c3);
    __syncthreads();
    if (tid < 64){
        float v = srow[tid];
        float t = v;
        t += __shfl_xor(t,1); t += __shfl_xor(t,2); t += __shfl_xor(t,4);
        t += __shfl_xor(t,8); t += __shfl_xor(t,16); t += __shfl_xor(t,32);
        if (tid==0) chansum[bgc] = t;
        rs[bgc*64 + tid] = v;
        cs[bgc*64 + tid] = scol[tid];
    }
    if (tid == 0){
        const float* xb = x + (size_t)bgc*4096;
        corners[bgc*4+0] = xb[0];
        corners[bgc*4+1] = xb[63];
        corners[bgc*4+2] = xb[63*64];
        corners[bgc*4+3] = xb[4095];
    }
}

// ---------------- K2: gates sh/sw (512 blocks) + weff/bconst (block 0) ----------------
__global__ __launch_bounds__(320) void k2_gates(const float* __restrict__ rs, const float* __restrict__ cs,
    const float* __restrict__ w1, const float* __restrict__ b1,
    const float* __restrict__ w3, const float* __restrict__ b3,
    const float* __restrict__ gn_b,
    float* __restrict__ sh, float* __restrict__ sw, float* __restrict__ weff)
{
    int bg = blockIdx.x, l = threadIdx.x;
    __shared__ float w1s[256], b1s[16];
    if (l < 256) w1s[l] = w1[l];
    if (l < 16)  b1s[l] = b1[l];
    __syncthreads();
    if (l < 128){
        float cat[16];
        bool isrow = l < 64;
        int p = isrow ? l : (l-64);
        const float* src = isrow ? rs : cs;
        #pragma unroll
        for (int c=0;c<16;++c) cat[c] = src[bg*1024 + c*64 + p]*(1.0f/64.0f);
        #pragma unroll
        for (int o=0;o<16;++o){
            float acc = b1s[o];
            #pragma unroll
            for (int c=0;c<16;++c) acc += w1s[o*16+c]*cat[c];
            float sg = sigmoidf_(acc);
            if (isrow) sh[bg*1024 + o*64 + p] = sg;
            else       sw[bg*1024 + o*64 + p] = sg;
        }
    } else if (bg == 0){
        // weff = sum_o a11[o]*w3[o,:]; bconst -> weff[144]
        float a11[16];
        float mx = gn_b[0];
        #pragma unroll
        for (int i=1;i<16;++i) mx = fmaxf(mx, gn_b[i]);
        float s=0.f;
        #pragma unroll
        for (int i=0;i<16;++i){ a11[i]=expf(gn_b[i]-mx); s+=a11[i]; }
        float inv = 1.0f/s;
        #pragma unroll
        for (int i=0;i<16;++i) a11[i]*=inv;
        int q = l - 128;            // 0..191
        if (q < 144){
            float acc=0.f;
            #pragma unroll
            for (int o=0;o<16;++o) acc += a11[o]*w3[o*144+q];
            weff[q]=acc;
        } else if (q == 144){
            float acc=0.f;
            #pragma unroll
            for (int o=0;o<16;++o) acc += a11[o]*b3[o];
            weff[144]=acc;          // bconst
        }
    }
}

// ---------------- K3: instance-norm stats of x1 = gx*sh_i*sw_j (8192 blocks, L3-hot) ----------------
__global__ __launch_bounds__(256) void k3_stats(const float* __restrict__ x,
    const float* __restrict__ sh, const float* __restrict__ sw,
    float* __restrict__ mu, float* __restrict__ rstd)
{
    int bgc = blockIdx.x, tid = threadIdx.x;
    int bg = bgc >> 4, c = bgc & 15;
    __shared__ float shv[64], swv[64];
    __shared__ float r1[4], r2[4];
    if (tid<64) shv[tid] = sh[bg*1024 + c*64 + tid];
    else if (tid<128) swv[tid-64] = sw[bg*1024 + c*64 + (tid-64)];
    __syncthreads();
    const float4* x4 = (const float4*)(x + (size_t)bgc*4096);
    float s1=0.f, s2=0.f;
    int jb = (tid&15)*4;
    #pragma unroll
    for (int it=0; it<4; ++it){
        int f = it*256+tid;
        float4 v = x4[f];
        int i = f>>4;
        float si = shv[i];
        float a0 = v.x*si*swv[jb+0];
        float a1 = v.y*si*swv[jb+1];
        float a2 = v.z*si*swv[jb+2];
        float a3 = v.w*si*swv[jb+3];
        s1 += a0+a1+a2+a3;
        s2 += a0*a0+a1*a1+a2*a2+a3*a3;
    }
    #pragma unroll
    for (int m=1; m<64; m<<=1){ s1 += __shfl_xor(s1,m); s2 += __shfl_xor(s2,m); }
    int lane = tid&63, wid = tid>>6;
    if (lane==0){ r1[wid]=s1; r2[wid]=s2; }
    __syncthreads();
    if (tid==0){
        float S1 = r1[0]+r1[1]+r1[2]+r1[3];
        float S2 = r2[0]+r2[1]+r2[2]+r2[3];
        float m = S1*(1.0f/4096.0f);
        float var = S2*(1.0f/4096.0f) - m*m;
        mu[bgc]=m;
        rstd[bgc]=rsqrtf(var+EPS);
    }
}

// ---------------- K4: analytic mean(x2) -> a21 -> alpha, cst (bconst folded) ----------------
__global__ __launch_bounds__(256) void k4_a21(const float* __restrict__ w3, const float* __restrict__ b3,
    const float* __restrict__ gn_w, const float* __restrict__ gn_b,
    const float* __restrict__ rs, const float* __restrict__ cs,
    const float* __restrict__ chansum, const float* __restrict__ corners,
    const float* __restrict__ mu, const float* __restrict__ rstd,
    const float* __restrict__ weff,
    float* __restrict__ alpha, float* __restrict__ cst)
{
    int bg = blockIdx.x, tid = threadIdx.x;
    __shared__ float w3s[2304];
    __shared__ float regs[144];
    __shared__ float m2[16];
    __shared__ float a21[16];
    #pragma unroll
    for (int k=0;k<9;++k) w3s[tid + k*256] = w3[tid + k*256];
    if (tid < 144){
        int c = tid/9, k = tid - c*9, ky = k/3, kx = k - ky*3;
        int bgc = bg*16 + c;
        float r = chansum[bgc];
        if (ky==0) r -= rs[bgc*64+63];
        if (ky==2) r -= rs[bgc*64+0];
        if (kx==0) r -= cs[bgc*64+63];
        if (kx==2) r -= cs[bgc*64+0];
        if (ky!=1 && kx!=1) r += corners[bgc*4 + ((ky==0)?2:0) + ((kx==0)?1:0)];
        regs[tid] = r;
    }
    __syncthreads();
    if (tid<16){
        float s=0.f;
        const float* wo = w3s + tid*144;
        for (int q=0;q<144;++q) s += wo[q]*regs[q];
        m2[tid] = b3[tid] + s*(1.0f/4096.0f);
    }
    __syncthreads();
    if (tid==0){
        float m = m2[0];
        for (int i=1;i<16;++i) m = fmaxf(m, m2[i]);
        float s=0.f, e[16];
        for (int i=0;i<16;++i){ e[i]=expf(m2[i]-m); s+=e[i]; }
        for (int i=0;i<16;++i) a21[i] = e[i]/s;
    }
    __syncthreads();
    if (tid<16){
        int bgc = bg*16+tid;
        alpha[bgc] = a21[tid]*gn_w[tid]*rstd[bgc];
    }
    if (tid==0){
        float cv = weff[144];   // bconst
        for (int c2=0;c2<16;++c2){
            int bgc = bg*16+c2;
            cv += a21[c2]*(gn_b[c2] - gn_w[c2]*rstd[bgc]*mu[bgc]);
        }
        cst[bg] = cv;
    }
}

// ---------------- K5: register-streaming conv + gating (R15-proven, 2048x256) ----------------
__global__ __launch_bounds__(256) void k5_wv(const float* __restrict__ x,
    const float* __restrict__ sh, const float* __restrict__ sw,
    const float* __restrict__ alpha, const float* __restrict__ cst,
    const float* __restrict__ weff,
    float* __restrict__ sigbuf, float* __restrict__ p2part)
{
    const int bid = blockIdx.x;        // bg*4 + quarter
    const int bg  = bid >> 2;
    const int quarter = bid & 3;
    const int tid = threadIdx.x;
    const int j   = tid & 63;
    const int w   = tid >> 6;
    __shared__ float red[4][16];

    const int r0 = __builtin_amdgcn_readfirstlane(quarter*16 + w*4);
    const float* xb  = x + (size_t)bg*65536;
    const float* shb = sh + bg*1024;
    const float* swb = sw + bg*1024;
    const float* alb = alpha + bg*16;
    const float cstv = cst[bg];

    float A0[4], A1[4], A2[4], G[4];
    float keep[16][4];
    #pragma unroll
    for (int r=0;r<4;++r){ A0[r]=0.f; A1[r]=0.f; A2[r]=0.f; G[r]=0.f; }

    #pragma unroll
    for (int c=0;c<16;++c){
        const float* xcc = xb + c*4096;
        const float* wq = weff + c*9;
        float w0=wq[0], w1_=wq[1], w2=wq[2];
        float w3_=wq[3], w4=wq[4], w5=wq[5];
        float w6=wq[6], w7=wq[7], w8=wq[8];
        float alc = alb[c];
        float swv = swb[c*64 + j];
        float v[6];
        #pragma unroll
        for (int k=0;k<6;++k){
            int t = r0 - 1 + k;
            int tc = t < 0 ? 0 : (t > 63 ? 63 : t);
            float val = xcc[tc*64 + j];
            v[k] = (t >= 0 && t < 64) ? val : 0.f;
        }
        #pragma unroll
        for (int r=0;r<4;++r) keep[c][r] = v[r+1];
        #pragma unroll
        for (int k=0;k<6;++k){
            if (k<=3){ A0[k]+=w0*v[k]; A1[k]+=w1_*v[k]; A2[k]+=w2*v[k]; }
            if (k>=1 && k<=4){
                A0[k-1]+=w3_*v[k]; A1[k-1]+=w4*v[k]; A2[k-1]+=w5*v[k];
                float u = alc * shb[c*64 + (r0+k-1)];
                G[k-1] += u * (swv * v[k]);
            }
            if (k>=2){ A0[k-2]+=w6*v[k]; A1[k-2]+=w7*v[k]; A2[k-2]+=w8*v[k]; }
        }
    }

    float sg[4];
    #pragma unroll
    for (int r=0;r<4;++r){
        float l = __shfl_up(A0[r], 1);
        if (j==0) l = 0.f;
        float rr = __shfl_down(A2[r], 1);
        if (j==63) rr = 0.f;
        float s = sigmoidf_(l + A1[r] + rr + G[r] + cstv);
        sg[r] = s;
        sigbuf[(size_t)bg*4096 + (r0+r)*64 + j] = s;
    }

    #pragma unroll
    for (int c=0;c<16;++c){
        float acc = keep[c][0]*sg[0] + keep[c][1]*sg[1]
                  + keep[c][2]*sg[2] + keep[c][3]*sg[3];
        #pragma unroll
        for (int m=1;m<64;m<<=1) acc += __shfl_xor(acc, m);
        if (j==0) red[w][c] = acc;
    }
    __syncthreads();
    if (tid<16){
        p2part[bid*16 + tid] = red[0][tid]+red[1][tid]+red[2][tid]+red[3][tid];
    }
}

// ---------------- K_SE12: fused se1 + p2 assembly (4 partials) + se2 ----------------
__global__ __launch_bounds__(512) void k_se12(const float* __restrict__ chansum,
    const float* __restrict__ p2part, const float* __restrict__ gamma,
    const float* __restrict__ cg_w1, const float* __restrict__ cg_b1,
    const float* __restrict__ cg_w2, const float* __restrict__ cg_b2,
    const float* __restrict__ ga_w1, const float* __restrict__ ga_b1,
    const float* __restrict__ ga_w2, const float* __restrict__ ga_b2,
    float* __restrict__ se1, float* __restrict__ se2)
{
    int b = blockIdx.x, tid = threadIdx.x;
    __shared__ float pv[512];
    __shared__ float hdn[32];
    __shared__ float se1_s[512];

    float cs_v = chansum[b*512+tid];
    pv[tid] = cs_v*(1.0f/4096.0f);
    __syncthreads();
    if (tid<32){
        float acc = cg_b1[tid];
        const float* wr = cg_w1 + tid*512;
        for (int k=0;k<512;++k) acc += wr[k]*pv[k];
        hdn[tid] = fmaxf(acc, 0.0f);
    }
    __syncthreads();
    {
        float acc = cg_b2[tid];
        const float* wr = cg_w2 + tid*32;
        #pragma unroll
        for (int k=0;k<32;++k) acc += wr[k]*hdn[k];
        float s1v = sigmoidf_(acc);
        se1_s[tid] = s1v;
        se1[b*512+tid] = s1v;
    }
    __syncthreads();
    {
        int bg = b*32 + (tid>>4);
        int c  = tid & 15;
        float praw = p2part[(bg*4+0)*16 + c] + p2part[(bg*4+1)*16 + c]
                   + p2part[(bg*4+2)*16 + c] + p2part[(bg*4+3)*16 + c];
        float g0 = gamma[0];
        pv[tid] = (praw + g0*se1_s[tid]*cs_v) * (1.0f/4096.0f);
    }
    __syncthreads();
    if (tid<32){
        float acc = ga_b1[tid];
        const float* wr = ga_w1 + tid*512;
        for (int k=0;k<512;++k) acc += wr[k]*pv[k];
        hdn[tid] = fmaxf(acc, 0.0f);
    }
    __syncthreads();
    {
        float acc = ga_b2[tid];
        const float* wr = ga_w2 + tid*32;
        #pragma unroll
        for (int k=0;k<32;++k) acc += wr[k]*hdn[k];
        se2[b*512+tid] = sigmoidf_(acc);
    }
}

// ---------------- K7: out = x * (sig + gamma*se1) * se2 (grid-stride) ----------------
__global__ __launch_bounds__(256) void k7_out(const float* __restrict__ x,
    const float* __restrict__ sigbuf, const float* __restrict__ se1,
    const float* __restrict__ se2, const float* __restrict__ gamma,
    float* __restrict__ out)
{
    const floatx4* x4 = (const floatx4*)x;
    const floatx4* s4 = (const floatx4*)sigbuf;
    floatx4* o4 = (floatx4*)out;
    float g0 = gamma[0];
    int idx = blockIdx.x*256 + threadIdx.x;
    int stride = gridDim.x*256;
    for (int g4 = idx; g4 < 8388608; g4 += stride){
        int e = g4 << 2;
        int bC = e >> 12;
        int pix4 = g4 & 1023;
        int bg = bC >> 4;
        floatx4 xv = x4[g4];
        floatx4 sg = s4[bg*1024 + pix4];
        float f1 = g0*se1[bC];
        float s2v = se2[bC];
        floatx4 ov;
        ov.x = xv.x*(sg.x+f1)*s2v;
        ov.y = xv.y*(sg.y+f1)*s2v;
        ov.z = xv.z*(sg.z+f1)*s2v;
        ov.w = xv.w*(sg.w+f1)*s2v;
        __builtin_nontemporal_store(ov, &o4[g4]);
    }
}

extern "C" void kernel_launch(void* const* d_in, const int* in_sizes, int n_in,
                              void* d_out, int out_size, void* d_ws, size_t ws_size,
                              hipStream_t stream)
{
    const float* x     = (const float*)d_in[0];
    const float* w1    = (const float*)d_in[1];
    const float* b1    = (const float*)d_in[2];
    const float* w3    = (const float*)d_in[3];
    const float* b3    = (const float*)d_in[4];
    const float* gn_w  = (const float*)d_in[5];
    const float* gn_b  = (const float*)d_in[6];
    const float* cg_w1 = (const float*)d_in[7];
    const float* cg_b1 = (const float*)d_in[8];
    const float* cg_w2 = (const float*)d_in[9];
    const float* cg_b2 = (const float*)d_in[10];
    const float* ga_w1 = (const float*)d_in[11];
    const float* ga_b1 = (const float*)d_in[12];
    const float* ga_w2 = (const float*)d_in[13];
    const float* ga_b2 = (const float*)d_in[14];
    const float* gamma = (const float*)d_in[15];
    float* out = (float*)d_out;
    float* ws  = (float*)d_ws;

    // workspace layout (float offsets)
    float* rs      = ws + 0;         // 524288
    float* cs      = ws + 524288;    // 524288
    float* sh      = ws + 1048576;   // 524288
    float* sw      = ws + 1572864;   // 524288
    float* chansum = ws + 2097152;   // 8192
    float* corners = ws + 2105344;   // 32768
    float* mu      = ws + 2138112;   // 8192
    float* rstd    = ws + 2146304;   // 8192
    float* alpha   = ws + 2154496;   // 8192
    float* cst     = ws + 2162688;   // 512
    float* weff    = ws + 2163200;   // 160 ([144]=bconst)
    float* sigbuf  = ws + 2163456;   // 2097152 (16B aligned)
    float* p2part  = ws + 4260608;   // 32768
    float* se1     = ws + 4293376;   // 8192
    float* se2     = ws + 4301568;   // 8192

    k1_rowcol<<<8192,256,0,stream>>>(x, rs, cs, chansum, corners);
    k2_gates<<<512,320,0,stream>>>(rs, cs, w1, b1, w3, b3, gn_b, sh, sw, weff);
    k3_stats<<<8192,256,0,stream>>>(x, sh, sw, mu, rstd);
    k4_a21<<<512,256,0,stream>>>(w3, b3, gn_w, gn_b, rs, cs, chansum, corners, mu, rstd, weff, alpha, cst);
    k5_wv<<<2048,256,0,stream>>>(x, sh, sw, alpha, cst, weff, sigbuf, p2part);
    k_se12<<<16,512,0,stream>>>(chansum, p2part, gamma, cg_w1, cg_b1, cg_w2, cg_b2,
                                ga_w1, ga_b1, ga_w2, ga_b2, se1, se2);
    k7_out<<<8192,256,0,stream>>>(x, sigbuf, se1, se2, gamma, out);
}

// Round 17
// 180.463 us; speedup vs baseline: 1.0766x; 1.0766x over previous
//
#include <hip/hip_runtime.h>
#include <math.h>

#define EPS 1e-5f

typedef float __attribute__((ext_vector_type(4))) floatx4;

__device__ __forceinline__ float sigmoidf_(float v){ return 1.0f/(1.0f+expf(-v)); }

// ---------------- KAB2: fused per-bg kernel (R12 base; phase-1 de-chained, phase-3 hoisted) ----------------
// 1024 threads. Phases 1-4: wave w = channel w (streamed). Phase 5: wave w = rows 4w..4w+3.
__global__ __launch_bounds__(1024) __attribute__((amdgpu_waves_per_eu(4,4)))
void kAB2(const float* __restrict__ x,
    const float* __restrict__ w1, const float* __restrict__ b1,
    const float* __restrict__ w3, const float* __restrict__ b3,
    const float* __restrict__ gn_w, const float* __restrict__ gn_b,
    float* __restrict__ chansum, float* __restrict__ sigbuf, float* __restrict__ p2part)
{
    const int bg = blockIdx.x;
    const int tid = threadIdx.x;
    const int w = tid >> 6;        // wave id
    const int lane = tid & 63;

    __shared__ float rs_s[16][64], cs_s[16][64];
    __shared__ float sh_s[16][64], sw_s[16][64];
    __shared__ float chs_s[16], corn_s[16][4], mu_s[16], rstd_s[16];
    __shared__ float w3s[2304], w1s[256], b1s[16];
    __shared__ float regs[144], m2[16], a21_s[16];
    __shared__ float weff_s[144], alpha_s[16], cb_s[2];
    __shared__ float red_s[16][16];

    for (int t=tid; t<2304; t+=1024) w3s[t] = w3[t];
    if (tid < 256) w1s[tid] = w1[tid];
    if (tid < 16)  b1s[tid] = b1[tid];
    rs_s[w][lane] = 0.0f;          // zero row-sum accumulators (atomicAdd targets)
    __syncthreads();

    const float* xc = x + (((size_t)bg<<4) + w)*4096;
    const float4* xc4 = (const float4*)xc;

    // ---- phase 1: col sums in regs, row sums via fire-and-forget LDS atomics ----
    {
        float c0=0.f,c1=0.f,c2=0.f,c3=0.f;
        #pragma unroll
        for (int it=0; it<16; ++it){
            float4 v = xc4[it*64 + lane];
            atomicAdd(&rs_s[w][it*4 + (lane>>4)], v.x+v.y+v.z+v.w);
            c0+=v.x; c1+=v.y; c2+=v.z; c3+=v.w;
        }
        c0 += __shfl_xor(c0,16); c0 += __shfl_xor(c0,32);
        c1 += __shfl_xor(c1,16); c1 += __shfl_xor(c1,32);
        c2 += __shfl_xor(c2,16); c2 += __shfl_xor(c2,32);
        c3 += __shfl_xor(c3,16); c3 += __shfl_xor(c3,32);
        float t = c0+c1+c2+c3;
        t += __shfl_xor(t,1); t += __shfl_xor(t,2);
        t += __shfl_xor(t,4); t += __shfl_xor(t,8);
        if (lane < 16){
            cs_s[w][lane*4+0]=c0; cs_s[w][lane*4+1]=c1;
            cs_s[w][lane*4+2]=c2; cs_s[w][lane*4+3]=c3;
        }
        if (lane==0){
            chs_s[w]=t;
            chansum[(bg<<4)+w]=t;
            corn_s[w][0]=xc[0]; corn_s[w][1]=xc[63];
            corn_s[w][2]=xc[4032]; corn_s[w][3]=xc[4095];
        }
    }
    __syncthreads();

    // ---- phase 2: gates sh/sw (LDS only) + weff/bconst ----
    {
        int p  = tid & 127;
        int o0 = tid >> 7;           // 0..7
        bool isrow = (p < 64);       // wave-uniform
        int pp = p & 63;
        float cat[16];
        #pragma unroll
        for (int cc=0; cc<16; ++cc)
            cat[cc] = (isrow ? rs_s[cc][pp] : cs_s[cc][pp]) * (1.0f/64.0f);
        #pragma unroll
        for (int t2=0; t2<2; ++t2){
            int o = o0 + t2*8;
            float acc = b1s[o];
            #pragma unroll
            for (int cc=0; cc<16; ++cc) acc += w1s[o*16+cc]*cat[cc];
            float sg = sigmoidf_(acc);
            if (isrow) sh_s[o][pp]=sg;
            else       sw_s[o][pp]=sg;
        }
    }
    if (tid < 145){
        float a11[16];
        {
            float mx = gn_b[0];
            #pragma unroll
            for (int i=1;i<16;++i) mx = fmaxf(mx, gn_b[i]);
            float s=0.f;
            #pragma unroll
            for (int i=0;i<16;++i){ a11[i]=expf(gn_b[i]-mx); s+=a11[i]; }
            float inv = 1.0f/s;
            #pragma unroll
            for (int i=0;i<16;++i) a11[i]*=inv;
        }
        if (tid<144){
            float acc=0.f;
            #pragma unroll
            for (int o=0;o<16;++o) acc += a11[o]*w3s[o*144+tid];
            weff_s[tid]=acc;
        } else {
            float acc=0.f;
            #pragma unroll
            for (int o=0;o<16;++o) acc += a11[o]*b3[o];
            cb_s[1]=acc;
        }
    }
    __syncthreads();

    // ---- phase 3: instance-norm stats of x1 = x*sh_i*sw_j (sh preloaded to regs) ----
    {
        int jb = (lane&15)*4;
        float sw0=sw_s[w][jb], sw1=sw_s[w][jb+1], sw2=sw_s[w][jb+2], sw3=sw_s[w][jb+3];
        float shr[16];
        #pragma unroll
        for (int it=0; it<16; ++it) shr[it] = sh_s[w][it*4+(lane>>4)];
        float s1=0.f, s2=0.f;
        #pragma unroll
        for (int it=0; it<16; ++it){
            float4 v = xc4[it*64+lane];
            float si = shr[it];
            float a0=v.x*si*sw0, a1=v.y*si*sw1, a2=v.z*si*sw2, a3=v.w*si*sw3;
            s1 += a0+a1+a2+a3;
            s2 += a0*a0+a1*a1+a2*a2+a3*a3;
        }
        #pragma unroll
        for (int mm=1;mm<64;mm<<=1){ s1+=__shfl_xor(s1,mm); s2+=__shfl_xor(s2,mm); }
        if (lane==0){
            float mu = s1*(1.0f/4096.0f);
            float var = s2*(1.0f/4096.0f) - mu*mu;
            mu_s[w]=mu; rstd_s[w]=rsqrtf(var+EPS);
        }
    }
    __syncthreads();

    // ---- phase 4: analytic mean(x2) -> a21 -> alpha, cst ----
    if (tid < 144){
        int c = tid/9, k = tid - c*9, ky = k/3, kx = k - ky*3;
        float r = chs_s[c];
        if (ky==0) r -= rs_s[c][63];
        if (ky==2) r -= rs_s[c][0];
        if (kx==0) r -= cs_s[c][63];
        if (kx==2) r -= cs_s[c][0];
        if (ky!=1 && kx!=1) r += corn_s[c][((ky==0)?2:0)+((kx==0)?1:0)];
        regs[tid] = r;
    }
    __syncthreads();
    if (tid<16){
        float s=0.f;
        const float* wo = w3s + tid*144;
        for (int q=0;q<144;++q) s += wo[q]*regs[q];
        m2[tid] = b3[tid] + s*(1.0f/4096.0f);
    }
    __syncthreads();
    if (tid==0){
        float mx = m2[0];
        for (int i=1;i<16;++i) mx = fmaxf(mx, m2[i]);
        float s=0.f, e[16];
        for (int i=0;i<16;++i){ e[i]=expf(m2[i]-mx); s+=e[i]; }
        for (int i=0;i<16;++i) a21_s[i]=e[i]/s;
    }
    __syncthreads();
    if (tid<16) alpha_s[tid] = a21_s[tid]*gn_w[tid]*rstd_s[tid];
    if (tid==0){
        float cv=0.f;
        for (int c2=0;c2<16;++c2)
            cv += a21_s[c2]*(gn_b[c2] - gn_w[c2]*rstd_s[c2]*mu_s[c2]);
        cb_s[0]=cv;
    }
    __syncthreads();

    // ---- phase 5: row-parallel conv+gating (wave w -> rows 4w..4w+3), psum from keep regs ----
    {
        const int j = lane;
        const int r0 = __builtin_amdgcn_readfirstlane(4*w);
        const float* xb = x + ((size_t)bg<<4)*4096;
        const float cstv = cb_s[0] + cb_s[1];

        float A0[4], A1[4], A2[4], G[4];
        float keep[16][4];
        #pragma unroll
        for (int r=0;r<4;++r){ A0[r]=0.f; A1[r]=0.f; A2[r]=0.f; G[r]=0.f; }

        #pragma unroll
        for (int c=0;c<16;++c){
            const float* xcc = xb + c*4096;
            float w0=weff_s[c*9+0], w1_=weff_s[c*9+1], w2=weff_s[c*9+2];
            float w3_=weff_s[c*9+3], w4=weff_s[c*9+4], w5=weff_s[c*9+5];
            float w6=weff_s[c*9+6], w7=weff_s[c*9+7], w8=weff_s[c*9+8];
            float alc = alpha_s[c];
            float swv = sw_s[c][j];
            float v[6];
            #pragma unroll
            for (int k=0;k<6;++k){
                int t = r0 - 1 + k;
                int tc = t < 0 ? 0 : (t > 63 ? 63 : t);
                float val = xcc[tc*64 + j];
                v[k] = (t >= 0 && t < 64) ? val : 0.f;
            }
            #pragma unroll
            for (int r=0;r<4;++r) keep[c][r] = v[r+1];
            #pragma unroll
            for (int k=0;k<6;++k){
                if (k<=3){ A0[k]+=w0*v[k]; A1[k]+=w1_*v[k]; A2[k]+=w2*v[k]; }
                if (k>=1 && k<=4){
                    A0[k-1]+=w3_*v[k]; A1[k-1]+=w4*v[k]; A2[k-1]+=w5*v[k];
                    float u = alc * sh_s[c][r0+k-1];   // wave-uniform LDS broadcast
                    G[k-1] += u * (swv * v[k]);
                }
                if (k>=2){ A0[k-2]+=w6*v[k]; A1[k-2]+=w7*v[k]; A2[k-2]+=w8*v[k]; }
            }
        }

        float sg[4];
        #pragma unroll
        for (int r=0;r<4;++r){
            float l = __shfl_up(A0[r], 1);
            if (j==0) l = 0.f;
            float rr = __shfl_down(A2[r], 1);
            if (j==63) rr = 0.f;
            float s = sigmoidf_(l + A1[r] + rr + G[r] + cstv);
            sg[r] = s;
            sigbuf[(size_t)bg*4096 + (r0+r)*64 + j] = s;
        }

        #pragma unroll
        for (int c=0;c<16;++c){
            float acc = keep[c][0]*sg[0] + keep[c][1]*sg[1]
                      + keep[c][2]*sg[2] + keep[c][3]*sg[3];
            #pragma unroll
            for (int mm=1;mm<64;mm<<=1) acc += __shfl_xor(acc, mm);
            if (j==0) red_s[w][c] = acc;
        }
    }
    __syncthreads();
    if (tid<16){
        float tot = 0.f;
        #pragma unroll
        for (int ww=0;ww<16;++ww) tot += red_s[ww][tid];
        p2part[(bg<<4)+tid] = tot;
    }
}

// ---------------- K_SE12: fused se1 + p2 assembly + se2, one block per batch b ----------------
__global__ __launch_bounds__(512) void k_se12(const float* __restrict__ chansum,
    const float* __restrict__ p2part, const float* __restrict__ gamma,
    const float* __restrict__ cg_w1, const float* __restrict__ cg_b1,
    const float* __restrict__ cg_w2, const float* __restrict__ cg_b2,
    const float* __restrict__ ga_w1, const float* __restrict__ ga_b1,
    const float* __restrict__ ga_w2, const float* __restrict__ ga_b2,
    float* __restrict__ se1, float* __restrict__ se2)
{
    int b = blockIdx.x, tid = threadIdx.x;
    __shared__ float pv[512];
    __shared__ float hdn[32];
    __shared__ float se1_s[512];

    float cs_v = chansum[b*512+tid];
    pv[tid] = cs_v*(1.0f/4096.0f);
    __syncthreads();
    if (tid<32){
        float acc = cg_b1[tid];
        const float* wr = cg_w1 + tid*512;
        for (int k=0;k<512;++k) acc += wr[k]*pv[k];
        hdn[tid] = fmaxf(acc, 0.0f);
    }
    __syncthreads();
    {
        float acc = cg_b2[tid];
        const float* wr = cg_w2 + tid*32;
        #pragma unroll
        for (int k=0;k<32;++k) acc += wr[k]*hdn[k];
        float s1v = sigmoidf_(acc);
        se1_s[tid] = s1v;
        se1[b*512+tid] = s1v;
    }
    __syncthreads();
    {
        float praw = p2part[b*512+tid];
        float g0 = gamma[0];
        pv[tid] = (praw + g0*se1_s[tid]*cs_v) * (1.0f/4096.0f);
    }
    __syncthreads();
    if (tid<32){
        float acc = ga_b1[tid];
        const float* wr = ga_w1 + tid*512;
        for (int k=0;k<512;++k) acc += wr[k]*pv[k];
        hdn[tid] = fmaxf(acc, 0.0f);
    }
    __syncthreads();
    {
        float acc = ga_b2[tid];
        const float* wr = ga_w2 + tid*32;
        #pragma unroll
        for (int k=0;k<32;++k) acc += wr[k]*hdn[k];
        se2[b*512+tid] = sigmoidf_(acc);
    }
}

// ---------------- K7: out = x * (sig + gamma*se1) * se2 (grid-stride) ----------------
__global__ __launch_bounds__(256) void k7_out(const float* __restrict__ x,
    const float* __restrict__ sigbuf, const float* __restrict__ se1,
    const float* __restrict__ se2, const float* __restrict__ gamma,
    float* __restrict__ out)
{
    const floatx4* x4 = (const floatx4*)x;
    const floatx4* s4 = (const floatx4*)sigbuf;
    floatx4* o4 = (floatx4*)out;
    float g0 = gamma[0];
    int idx = blockIdx.x*256 + threadIdx.x;
    int stride = gridDim.x*256;
    for (int g4 = idx; g4 < 8388608; g4 += stride){
        int e = g4 << 2;
        int bC = e >> 12;
        int pix4 = g4 & 1023;
        int bg = bC >> 4;
        floatx4 xv = x4[g4];
        floatx4 sg = s4[bg*1024 + pix4];
        float f1 = g0*se1[bC];
        float s2v = se2[bC];
        floatx4 ov;
        ov.x = xv.x*(sg.x+f1)*s2v;
        ov.y = xv.y*(sg.y+f1)*s2v;
        ov.z = xv.z*(sg.z+f1)*s2v;
        ov.w = xv.w*(sg.w+f1)*s2v;
        __builtin_nontemporal_store(ov, &o4[g4]);
    }
}

extern "C" void kernel_launch(void* const* d_in, const int* in_sizes, int n_in,
                              void* d_out, int out_size, void* d_ws, size_t ws_size,
                              hipStream_t stream)
{
    const float* x     = (const float*)d_in[0];
    const float* w1    = (const float*)d_in[1];
    const float* b1    = (const float*)d_in[2];
    const float* w3    = (const float*)d_in[3];
    const float* b3    = (const float*)d_in[4];
    const float* gn_w  = (const float*)d_in[5];
    const float* gn_b  = (const float*)d_in[6];
    const float* cg_w1 = (const float*)d_in[7];
    const float* cg_b1 = (const float*)d_in[8];
    const float* cg_w2 = (const float*)d_in[9];
    const float* cg_b2 = (const float*)d_in[10];
    const float* ga_w1 = (const float*)d_in[11];
    const float* ga_b1 = (const float*)d_in[12];
    const float* ga_w2 = (const float*)d_in[13];
    const float* ga_b2 = (const float*)d_in[14];
    const float* gamma = (const float*)d_in[15];
    float* out = (float*)d_out;
    float* ws  = (float*)d_ws;

    // workspace layout (float offsets)
    float* chansum = ws + 0;         // 8192
    float* p2part  = ws + 8192;      // 8192
    float* se1     = ws + 16384;     // 8192
    float* se2     = ws + 24576;     // 8192
    float* sigbuf  = ws + 32768;     // 2097152 (16B aligned)

    kAB2<<<512,1024,0,stream>>>(x, w1, b1, w3, b3, gn_w, gn_b, chansum, sigbuf, p2part);
    k_se12<<<16,512,0,stream>>>(chansum, p2part, gamma, cg_w1, cg_b1, cg_w2, cg_b2,
                                ga_w1, ga_b1, ga_w2, ga_b2, se1, se2);
    k7_out<<<8192,256,0,stream>>>(x, sigbuf, se1, se2, gamma, out);
}

// Round 18
// 133.172 us; speedup vs baseline: 1.4589x; 1.3551x over previous
//
#include <hip/hip_runtime.h>
#include <math.h>

#define EPS 1e-5f

typedef float __attribute__((ext_vector_type(4))) floatx4;

__device__ __forceinline__ float sigmoidf_(float v){ return 1.0f/(1.0f+expf(-v)); }

// ---------------- KAB2: fused per-bg kernel (R12 exact) ----------------
// 1024 threads. Phases 1-4: wave w = channel w (streamed, no retention).
// Phase 5: wave w = output rows 4w..4w+3, loops 16 channels; keep[16][4] lives
// only inside the barrier-free phase-5 region (unified VGPR/AGPR file holds it).
__global__ __launch_bounds__(1024) __attribute__((amdgpu_waves_per_eu(4,4)))
void kAB2(const float* __restrict__ x,
    const float* __restrict__ w1, const float* __restrict__ b1,
    const float* __restrict__ w3, const float* __restrict__ b3,
    const float* __restrict__ gn_w, const float* __restrict__ gn_b,
    float* __restrict__ chansum, float* __restrict__ sigbuf, float* __restrict__ p2part)
{
    const int bg = blockIdx.x;
    const int tid = threadIdx.x;
    const int w = tid >> 6;        // wave id
    const int lane = tid & 63;

    __shared__ float rs_s[16][64], cs_s[16][64];
    __shared__ float sh_s[16][64], sw_s[16][64];
    __shared__ float chs_s[16], corn_s[16][4], mu_s[16], rstd_s[16];
    __shared__ float w3s[2304], w1s[256], b1s[16];
    __shared__ float regs[144], m2[16], a21_s[16];
    __shared__ float weff_s[144], alpha_s[16], cb_s[2];
    __shared__ float red_s[16][16];

    for (int t=tid; t<2304; t+=1024) w3s[t] = w3[t];
    if (tid < 256) w1s[tid] = w1[tid];
    if (tid < 16)  b1s[tid] = b1[tid];

    const float* xc = x + (((size_t)bg<<4) + w)*4096;
    const float4* xc4 = (const float4*)xc;

    // ---- phase 1: row sums / col sums / total / corners (streamed) ----
    {
        float c0=0.f,c1=0.f,c2=0.f,c3=0.f;
        #pragma unroll
        for (int it=0; it<16; ++it){
            float4 v = xc4[it*64 + lane];
            float rsum = v.x+v.y+v.z+v.w;
            rsum += __shfl_xor(rsum,1); rsum += __shfl_xor(rsum,2);
            rsum += __shfl_xor(rsum,4); rsum += __shfl_xor(rsum,8);
            if ((lane&15)==0) rs_s[w][it*4 + (lane>>4)] = rsum;
            c0+=v.x; c1+=v.y; c2+=v.z; c3+=v.w;
        }
        c0 += __shfl_xor(c0,16); c0 += __shfl_xor(c0,32);
        c1 += __shfl_xor(c1,16); c1 += __shfl_xor(c1,32);
        c2 += __shfl_xor(c2,16); c2 += __shfl_xor(c2,32);
        c3 += __shfl_xor(c3,16); c3 += __shfl_xor(c3,32);
        float tsum = c0+c1+c2+c3;
        tsum += __shfl_xor(tsum,1); tsum += __shfl_xor(tsum,2);
        tsum += __shfl_xor(tsum,4); tsum += __shfl_xor(tsum,8);
        if (lane < 16){
            cs_s[w][lane*4+0]=c0; cs_s[w][lane*4+1]=c1;
            cs_s[w][lane*4+2]=c2; cs_s[w][lane*4+3]=c3;
        }
        if (lane==0){
            chs_s[w]=tsum;
            chansum[(bg<<4)+w]=tsum;
            corn_s[w][0]=xc[0]; corn_s[w][1]=xc[63];
            corn_s[w][2]=xc[4032]; corn_s[w][3]=xc[4095];
        }
    }
    __syncthreads();

    // ---- phase 2: gates sh/sw (LDS only) + weff/bconst ----
    {
        int p  = tid & 127;
        int o0 = tid >> 7;           // 0..7
        bool isrow = (p < 64);       // wave-uniform
        int pp = p & 63;
        float cat[16];
        #pragma unroll
        for (int cc=0; cc<16; ++cc)
            cat[cc] = (isrow ? rs_s[cc][pp] : cs_s[cc][pp]) * (1.0f/64.0f);
        #pragma unroll
        for (int t2=0; t2<2; ++t2){
            int o = o0 + t2*8;
            float acc = b1s[o];
            #pragma unroll
            for (int cc=0; cc<16; ++cc) acc += w1s[o*16+cc]*cat[cc];
            float sg = sigmoidf_(acc);
            if (isrow) sh_s[o][pp]=sg;
            else       sw_s[o][pp]=sg;
        }
    }
    if (tid < 145){
        float a11[16];
        {
            float mx = gn_b[0];
            #pragma unroll
            for (int i=1;i<16;++i) mx = fmaxf(mx, gn_b[i]);
            float s=0.f;
            #pragma unroll
            for (int i=0;i<16;++i){ a11[i]=expf(gn_b[i]-mx); s+=a11[i]; }
            float inv = 1.0f/s;
            #pragma unroll
            for (int i=0;i<16;++i) a11[i]*=inv;
        }
        if (tid<144){
            float acc=0.f;
            #pragma unroll
            for (int o=0;o<16;++o) acc += a11[o]*w3s[o*144+tid];
            weff_s[tid]=acc;
        } else {
            float acc=0.f;
            #pragma unroll
            for (int o=0;o<16;++o) acc += a11[o]*b3[o];
            cb_s[1]=acc;
        }
    }
    __syncthreads();

    // ---- phase 3: instance-norm stats of x1 = x*sh_i*sw_j (L2/L3-hot re-read) ----
    {
        int jb = (lane&15)*4;
        float sw0=sw_s[w][jb], sw1=sw_s[w][jb+1], sw2=sw_s[w][jb+2], sw3=sw_s[w][jb+3];
        float s1=0.f, s2=0.f;
        #pragma unroll
        for (int it=0; it<16; ++it){
            float4 v = xc4[it*64+lane];
            float si = sh_s[w][it*4+(lane>>4)];
            float a0=v.x*si*sw0, a1=v.y*si*sw1, a2=v.z*si*sw2, a3=v.w*si*sw3;
            s1 += a0+a1+a2+a3;
            s2 += a0*a0+a1*a1+a2*a2+a3*a3;
        }
        #pragma unroll
        for (int mm=1;mm<64;mm<<=1){ s1+=__shfl_xor(s1,mm); s2+=__shfl_xor(s2,mm); }
        if (lane==0){
            float mu = s1*(1.0f/4096.0f);
            float var = s2*(1.0f/4096.0f) - mu*mu;
            mu_s[w]=mu; rstd_s[w]=rsqrtf(var+EPS);
        }
    }
    __syncthreads();

    // ---- phase 4: analytic mean(x2) -> a21 -> alpha, cst ----
    if (tid < 144){
        int c = tid/9, k = tid - c*9, ky = k/3, kx = k - ky*3;
        float r = chs_s[c];
        if (ky==0) r -= rs_s[c][63];
        if (ky==2) r -= rs_s[c][0];
        if (kx==0) r -= cs_s[c][63];
        if (kx==2) r -= cs_s[c][0];
        if (ky!=1 && kx!=1) r += corn_s[c][((ky==0)?2:0)+((kx==0)?1:0)];
        regs[tid] = r;
    }
    __syncthreads();
    if (tid<16){
        float s=0.f;
        const float* wo = w3s + tid*144;
        for (int q=0;q<144;++q) s += wo[q]*regs[q];
        m2[tid] = b3[tid] + s*(1.0f/4096.0f);
    }
    __syncthreads();
    if (tid==0){
        float mx = m2[0];
        for (int i=1;i<16;++i) mx = fmaxf(mx, m2[i]);
        float s=0.f, e[16];
        for (int i=0;i<16;++i){ e[i]=expf(m2[i]-mx); s+=e[i]; }
        for (int i=0;i<16;++i) a21_s[i]=e[i]/s;
    }
    __syncthreads();
    if (tid<16) alpha_s[tid] = a21_s[tid]*gn_w[tid]*rstd_s[tid];
    if (tid==0){
        float cv=0.f;
        for (int c2=0;c2<16;++c2)
            cv += a21_s[c2]*(gn_b[c2] - gn_w[c2]*rstd_s[c2]*mu_s[c2]);
        cb_s[0]=cv;
    }
    __syncthreads();

    // ---- phase 5: row-parallel conv+gating (wave w -> rows 4w..4w+3), psum from keep regs ----
    {
        const int j = lane;
        const int r0 = __builtin_amdgcn_readfirstlane(4*w);
        const float* xb = x + ((size_t)bg<<4)*4096;
        const float cstv = cb_s[0] + cb_s[1];

        float A0[4], A1[4], A2[4], G[4];
        float keep[16][4];
        #pragma unroll
        for (int r=0;r<4;++r){ A0[r]=0.f; A1[r]=0.f; A2[r]=0.f; G[r]=0.f; }

        #pragma unroll
        for (int c=0;c<16;++c){
            const float* xcc = xb + c*4096;
            float w0=weff_s[c*9+0], w1_=weff_s[c*9+1], w2=weff_s[c*9+2];
            float w3_=weff_s[c*9+3], w4=weff_s[c*9+4], w5=weff_s[c*9+5];
            float w6=weff_s[c*9+6], w7=weff_s[c*9+7], w8=weff_s[c*9+8];
            float alc = alpha_s[c];
            float swv = sw_s[c][j];
            float v[6];
            #pragma unroll
            for (int k=0;k<6;++k){
                int t = r0 - 1 + k;
                int tc = t < 0 ? 0 : (t > 63 ? 63 : t);
                float val = xcc[tc*64 + j];
                v[k] = (t >= 0 && t < 64) ? val : 0.f;
            }
            #pragma unroll
            for (int r=0;r<4;++r) keep[c][r] = v[r+1];
            #pragma unroll
            for (int k=0;k<6;++k){
                if (k<=3){ A0[k]+=w0*v[k]; A1[k]+=w1_*v[k]; A2[k]+=w2*v[k]; }
                if (k>=1 && k<=4){
                    A0[k-1]+=w3_*v[k]; A1[k-1]+=w4*v[k]; A2[k-1]+=w5*v[k];
                    float u = alc * sh_s[c][r0+k-1];   // wave-uniform LDS broadcast
                    G[k-1] += u * (swv * v[k]);
                }
                if (k>=2){ A0[k-2]+=w6*v[k]; A1[k-2]+=w7*v[k]; A2[k-2]+=w8*v[k]; }
            }
        }

        float sg[4];
        #pragma unroll
        for (int r=0;r<4;++r){
            float l = __shfl_up(A0[r], 1);
            if (j==0) l = 0.f;
            float rr = __shfl_down(A2[r], 1);
            if (j==63) rr = 0.f;
            float s = sigmoidf_(l + A1[r] + rr + G[r] + cstv);
            sg[r] = s;
            sigbuf[(size_t)bg*4096 + (r0+r)*64 + j] = s;
        }

        #pragma unroll
        for (int c=0;c<16;++c){
            float acc = keep[c][0]*sg[0] + keep[c][1]*sg[1]
                      + keep[c][2]*sg[2] + keep[c][3]*sg[3];
            #pragma unroll
            for (int mm=1;mm<64;mm<<=1) acc += __shfl_xor(acc, mm);
            if (j==0) red_s[w][c] = acc;
        }
    }
    __syncthreads();
    if (tid<16){
        float tot = 0.f;
        #pragma unroll
        for (int ww=0;ww<16;++ww) tot += red_s[ww][tid];
        p2part[(bg<<4)+tid] = tot;
    }
}

// ---------------- K_SE12: fused se1 + p2 assembly + se2 (hidden layers wave-parallel) ----------------
__global__ __launch_bounds__(512) void k_se12(const float* __restrict__ chansum,
    const float* __restrict__ p2part, const float* __restrict__ gamma,
    const float* __restrict__ cg_w1, const float* __restrict__ cg_b1,
    const float* __restrict__ cg_w2, const float* __restrict__ cg_b2,
    const float* __restrict__ ga_w1, const float* __restrict__ ga_b1,
    const float* __restrict__ ga_w2, const float* __restrict__ ga_b2,
    float* __restrict__ se1, float* __restrict__ se2)
{
    int b = blockIdx.x, tid = threadIdx.x;
    __shared__ float pv[512];
    __shared__ float hdn[32];
    __shared__ float se1_s[512];
    const int n = tid >> 4;        // neuron 0..31 (16 threads each)
    const int cch = tid & 15;      // chunk 0..15 (32 elements each)

    float cs_v = chansum[b*512+tid];
    pv[tid] = cs_v*(1.0f/4096.0f);
    __syncthreads();
    {   // hidden1: 16 threads per neuron, shuffle-reduce
        const float* wr = cg_w1 + n*512 + cch*32;
        const float* pvc = pv + cch*32;
        float acc = 0.f;
        #pragma unroll
        for (int k=0;k<32;++k) acc += wr[k]*pvc[k];
        acc += __shfl_xor(acc,1); acc += __shfl_xor(acc,2);
        acc += __shfl_xor(acc,4); acc += __shfl_xor(acc,8);
        if (cch==0) hdn[n] = fmaxf(acc + cg_b1[n], 0.0f);
    }
    __syncthreads();
    {
        float acc = cg_b2[tid];
        const float* wr = cg_w2 + tid*32;
        #pragma unroll
        for (int k=0;k<32;++k) acc += wr[k]*hdn[k];
        float s1v = sigmoidf_(acc);
        se1_s[tid] = s1v;
        se1[b*512+tid] = s1v;
    }
    __syncthreads();
    {
        float praw = p2part[b*512+tid];
        float g0 = gamma[0];
        pv[tid] = (praw + g0*se1_s[tid]*cs_v) * (1.0f/4096.0f);
    }
    __syncthreads();
    {   // hidden2: 16 threads per neuron, shuffle-reduce
        const float* wr = ga_w1 + n*512 + cch*32;
        const float* pvc = pv + cch*32;
        float acc = 0.f;
        #pragma unroll
        for (int k=0;k<32;++k) acc += wr[k]*pvc[k];
        acc += __shfl_xor(acc,1); acc += __shfl_xor(acc,2);
        acc += __shfl_xor(acc,4); acc += __shfl_xor(acc,8);
        if (cch==0) hdn[n] = fmaxf(acc + ga_b1[n], 0.0f);
    }
    __syncthreads();
    {
        float acc = ga_b2[tid];
        const float* wr = ga_w2 + tid*32;
        #pragma unroll
        for (int k=0;k<32;++k) acc += wr[k]*hdn[k];
        se2[b*512+tid] = sigmoidf_(acc);
    }
}

// ---------------- K7: out = x * (sig + gamma*se1) * se2 (grid-stride) ----------------
__global__ __launch_bounds__(256) void k7_out(const float* __restrict__ x,
    const float* __restrict__ sigbuf, const float* __restrict__ se1,
    const float* __restrict__ se2, const float* __restrict__ gamma,
    float* __restrict__ out)
{
    const floatx4* x4 = (const floatx4*)x;
    const floatx4* s4 = (const floatx4*)sigbuf;
    floatx4* o4 = (floatx4*)out;
    float g0 = gamma[0];
    int idx = blockIdx.x*256 + threadIdx.x;
    int stride = gridDim.x*256;
    for (int g4 = idx; g4 < 8388608; g4 += stride){
        int e = g4 << 2;
        int bC = e >> 12;
        int pix4 = g4 & 1023;
        int bg = bC >> 4;
        floatx4 xv = x4[g4];
        floatx4 sg = s4[bg*1024 + pix4];
        float f1 = g0*se1[bC];
        float s2v = se2[bC];
        floatx4 ov;
        ov.x = xv.x*(sg.x+f1)*s2v;
        ov.y = xv.y*(sg.y+f1)*s2v;
        ov.z = xv.z*(sg.z+f1)*s2v;
        ov.w = xv.w*(sg.w+f1)*s2v;
        __builtin_nontemporal_store(ov, &o4[g4]);
    }
}

extern "C" void kernel_launch(void* const* d_in, const int* in_sizes, int n_in,
                              void* d_out, int out_size, void* d_ws, size_t ws_size,
                              hipStream_t stream)
{
    const float* x     = (const float*)d_in[0];
    const float* w1    = (const float*)d_in[1];
    const float* b1    = (const float*)d_in[2];
    const float* w3    = (const float*)d_in[3];
    const float* b3    = (const float*)d_in[4];
    const float* gn_w  = (const float*)d_in[5];
    const float* gn_b  = (const float*)d_in[6];
    const float* cg_w1 = (const float*)d_in[7];
    const float* cg_b1 = (const float*)d_in[8];
    const float* cg_w2 = (const float*)d_in[9];
    const float* cg_b2 = (const float*)d_in[10];
    const float* ga_w1 = (const float*)d_in[11];
    const float* ga_b1 = (const float*)d_in[12];
    const float* ga_w2 = (const float*)d_in[13];
    const float* ga_b2 = (const float*)d_in[14];
    const float* gamma = (const float*)d_in[15];
    float* out = (float*)d_out;
    float* ws  = (float*)d_ws;

    // workspace layout (float offsets)
    float* chansum = ws + 0;         // 8192
    float* p2part  = ws + 8192;      // 8192
    float* se1     = ws + 16384;     // 8192
    float* se2     = ws + 24576;     // 8192
    float* sigbuf  = ws + 32768;     // 2097152 (16B aligned)

    kAB2<<<512,1024,0,stream>>>(x, w1, b1, w3, b3, gn_w, gn_b, chansum, sigbuf, p2part);
    k_se12<<<16,512,0,stream>>>(chansum, p2part, gamma, cg_w1, cg_b1, cg_w2, cg_b2,
                                ga_w1, ga_b1, ga_w2, ga_b2, se1, se2);
    k7_out<<<8192,256,0,stream>>>(x, sigbuf, se1, se2, gamma, out);
}